// Round 1
// baseline (545.584 us; speedup 1.0000x reference)
//
#include <hip/hip_runtime.h>

#define N_NODES 50000
#define N_EDGES 600000

// ---------------- CSR build ----------------

__global__ void count_deg_kernel(const int* __restrict__ dst, int* __restrict__ deg, int ne) {
    int e = blockIdx.x * blockDim.x + threadIdx.x;
    if (e < ne) atomicAdd(&deg[dst[e]], 1);
}

__global__ __launch_bounds__(1024) void scan_kernel(const int* __restrict__ deg,
                                                    int* __restrict__ off,
                                                    int* __restrict__ cur, int n) {
    __shared__ int sums[1024];
    int tid = threadIdx.x;
    int ch = (n + 1023) / 1024;
    int start = tid * ch;
    int end = min(start + ch, n);
    int s = 0;
    for (int i = start; i < end; ++i) s += deg[i];
    sums[tid] = s;
    __syncthreads();
    for (int d = 1; d < 1024; d <<= 1) {
        int v = (tid >= d) ? sums[tid - d] : 0;
        __syncthreads();
        sums[tid] += v;
        __syncthreads();
    }
    int run = (tid == 0) ? 0 : sums[tid - 1];  // exclusive prefix
    for (int i = start; i < end; ++i) {
        off[i] = run;
        cur[i] = run;
        run += deg[i];
    }
    if (tid == 1023) off[n] = run;  // chunks past n are empty -> run == total
}

__global__ void fill_csr_kernel(const int* __restrict__ src, const int* __restrict__ dst,
                                int* __restrict__ cur, int* __restrict__ ssrc, int ne) {
    int e = blockIdx.x * blockDim.x + threadIdx.x;
    if (e < ne) {
        int p = atomicAdd(&cur[dst[e]], 1);
        ssrc[p] = src[e];
    }
}

// ---------------- dual GEMM:  S = A@Ws + b,  T = A@Wn ----------------
// A: [M][128] row-major. Ws,Wn: [128][dout]. Virtual B = [Ws|Wn] -> [128][2*dout].
// Tile: 64 rows x 64 cols, 256 threads, 4x4 micro-tile, BK=64.

#define BM 64
#define BN 64
#define BK 64
#define KDIM 128

__global__ __launch_bounds__(256) void gemm_dual_kernel(
    const float* __restrict__ A,
    const float* __restrict__ Ws, const float* __restrict__ Wn,
    const float* __restrict__ bias,
    float* __restrict__ S, float* __restrict__ T,
    int M, int dout)
{
    const int dout2 = 2 * dout;
    __shared__ float As[BK][BM + 4];  // transposed: As[k][m]; pad 4 keeps float4 align, kills conflicts
    __shared__ float Bs[BK][BN];

    const int bm = blockIdx.x * BM;
    const int bn = blockIdx.y * BN;
    const int tid = threadIdx.x;
    const int tx = tid & 15;   // col group 0..15
    const int ty = tid >> 4;   // row group 0..15

    float acc[4][4] = {};

    for (int k0 = 0; k0 < KDIM; k0 += BK) {
        // stage A chunk: 64 rows x 64 k -> As[k][m]   (1024 float4, 4 per thread)
        #pragma unroll
        for (int i = 0; i < 4; ++i) {
            int idx = tid + i * 256;      // 0..1023
            int row = idx >> 4;           // 0..63
            int kq  = idx & 15;           // float4 index along k
            int grow = bm + row;
            float4 v = make_float4(0.f, 0.f, 0.f, 0.f);
            if (grow < M)
                v = *(const float4*)(A + (long)grow * KDIM + k0 + kq * 4);
            As[kq * 4 + 0][row] = v.x;
            As[kq * 4 + 1][row] = v.y;
            As[kq * 4 + 2][row] = v.z;
            As[kq * 4 + 3][row] = v.w;
        }
        // stage B chunk: Bs[kk][col] from [Ws|Wn]
        #pragma unroll
        for (int i = 0; i < 4; ++i) {
            int idx = tid + i * 256;
            int kk = idx >> 4;            // 0..63
            int cq = idx & 15;            // float4 col group
            int col = bn + cq * 4;
            int krow = k0 + kk;
            float4 v = make_float4(0.f, 0.f, 0.f, 0.f);
            if (col < dout) {
                v = *(const float4*)(Ws + (long)krow * dout + col);
            } else if (col < dout2) {
                v = *(const float4*)(Wn + (long)krow * dout + (col - dout));
            }
            *(float4*)&Bs[kk][cq * 4] = v;
        }
        __syncthreads();

        #pragma unroll
        for (int k = 0; k < BK; ++k) {
            float4 a4 = *(const float4*)&As[k][ty * 4];
            float4 b4 = *(const float4*)&Bs[k][tx * 4];
            float av[4] = {a4.x, a4.y, a4.z, a4.w};
            float bv[4] = {b4.x, b4.y, b4.z, b4.w};
            #pragma unroll
            for (int i = 0; i < 4; ++i)
                #pragma unroll
                for (int j = 0; j < 4; ++j)
                    acc[i][j] = fmaf(av[i], bv[j], acc[i][j]);
        }
        __syncthreads();
    }

    // epilogue
    #pragma unroll
    for (int i = 0; i < 4; ++i) {
        int grow = bm + ty * 4 + i;
        if (grow >= M) continue;
        #pragma unroll
        for (int j = 0; j < 4; ++j) {
            int col = bn + tx * 4 + j;
            if (col < dout) {
                S[(long)grow * dout + col] = acc[i][j] + bias[col];
            } else if (col < dout2) {
                T[(long)grow * dout + (col - dout)] = acc[i][j];
            }
        }
    }
}

// ---------------- aggregation: out[n] = act( S[n] + (sum_{e in in(n)} T[src_e]) / deg ) ----

template <int RELU>
__global__ void agg_kernel(const float* __restrict__ S, const float* __restrict__ T,
                           const int* __restrict__ off, const int* __restrict__ ssrc,
                           float* __restrict__ out, int dout)
{
    int n = blockIdx.x;
    int c = threadIdx.x;
    if (c >= dout) return;
    int a = off[n];
    int b = off[n + 1];
    float acc = 0.f;
    int i = a;
    for (; i + 3 < b; i += 4) {
        int s0 = ssrc[i], s1 = ssrc[i + 1], s2 = ssrc[i + 2], s3 = ssrc[i + 3];
        float v0 = T[(long)s0 * dout + c];
        float v1 = T[(long)s1 * dout + c];
        float v2 = T[(long)s2 * dout + c];
        float v3 = T[(long)s3 * dout + c];
        acc += (v0 + v1) + (v2 + v3);
    }
    for (; i < b; ++i) acc += T[(long)ssrc[i] * dout + c];
    int deg = b - a;
    float scale = (deg > 0) ? (1.0f / (float)deg) : 0.f;
    float v = S[(long)n * dout + c] + acc * scale;
    if (RELU) v = fmaxf(v, 0.f);
    out[(long)n * dout + c] = v;
}

// ---------------- launch ----------------

extern "C" void kernel_launch(void* const* d_in, const int* in_sizes, int n_in,
                              void* d_out, int out_size, void* d_ws, size_t ws_size,
                              hipStream_t stream) {
    const float* feat = (const float*)d_in[0];
    const int*   src  = (const int*)d_in[1];
    const int*   dst  = (const int*)d_in[2];
    const float* ws0  = (const float*)d_in[3];
    const float* wn0  = (const float*)d_in[4];
    const float* b0   = (const float*)d_in[5];
    const float* ws1  = (const float*)d_in[6];
    const float* wn1  = (const float*)d_in[7];
    const float* b1   = (const float*)d_in[8];
    const float* ws2  = (const float*)d_in[9];
    const float* wn2  = (const float*)d_in[10];
    const float* b2   = (const float*)d_in[11];

    const int N = N_NODES;
    const int NE = N_EDGES;

    char* ws = (char*)d_ws;
    // workspace layout (256-aligned)
    int*   offsets = (int*)(ws + 0);            // 50001 ints
    int*   cursor  = (int*)(ws + 200704);       // 50000 ints
    int*   degi    = (int*)(ws + 401408);       // 50000 ints
    int*   ssrc    = (int*)(ws + 602112);       // 600000 ints
    float* hbuf    = (float*)(ws + 3002368);    // 50000*128 f32
    float* sbuf    = (float*)(ws + 28602368);   // 50000*128 f32
    float* tbuf    = (float*)(ws + 54202368);   // 50000*128 f32  (end ~79.8 MB)

    // ---- CSR build (graph is identical every call; rebuilt each launch for capture-safety) ----
    hipMemsetAsync(degi, 0, (size_t)N * sizeof(int), stream);
    count_deg_kernel<<<(NE + 255) / 256, 256, 0, stream>>>(dst, degi, NE);
    scan_kernel<<<1, 1024, 0, stream>>>(degi, offsets, cursor, N);
    fill_csr_kernel<<<(NE + 255) / 256, 256, 0, stream>>>(src, dst, cursor, ssrc, NE);

    const int gx = (N + BM - 1) / BM;  // 782

    // ---- layer 0: feat -> hbuf (relu) ----
    gemm_dual_kernel<<<dim3(gx, 4), 256, 0, stream>>>(feat, ws0, wn0, b0, sbuf, tbuf, N, 128);
    agg_kernel<1><<<N, 128, 0, stream>>>(sbuf, tbuf, offsets, ssrc, hbuf, 128);

    // ---- layer 1: hbuf -> hbuf (relu) ----
    gemm_dual_kernel<<<dim3(gx, 4), 256, 0, stream>>>(hbuf, ws1, wn1, b1, sbuf, tbuf, N, 128);
    agg_kernel<1><<<N, 128, 0, stream>>>(sbuf, tbuf, offsets, ssrc, hbuf, 128);

    // ---- layer 2: hbuf -> d_out (no relu) ----
    gemm_dual_kernel<<<dim3(gx, 2), 256, 0, stream>>>(hbuf, ws2, wn2, b2, sbuf, tbuf, N, 40);
    agg_kernel<0><<<N, 64, 0, stream>>>(sbuf, tbuf, offsets, ssrc, (float*)d_out, 40);
}

// Round 2
// 447.587 us; speedup vs baseline: 1.2189x; 1.2189x over previous
//
#include <hip/hip_runtime.h>

#define N_NODES 50000
#define N_EDGES 600000

// ---------------- CSR build ----------------

__global__ void count_deg_kernel(const int* __restrict__ dst, int* __restrict__ deg, int ne) {
    int e = blockIdx.x * blockDim.x + threadIdx.x;
    if (e < ne) atomicAdd(&deg[dst[e]], 1);
}

// ---- 3-pass hierarchical exclusive scan of deg[0..n) -> off/cur, off[n]=total ----
// Pass 1: per-block (256-elem chunk) sums.
__global__ __launch_bounds__(256) void block_sums_kernel(const int* __restrict__ deg,
                                                         int* __restrict__ bsum, int n) {
    __shared__ int s[256];
    int t = threadIdx.x;
    int i = blockIdx.x * 256 + t;
    s[t] = (i < n) ? deg[i] : 0;
    __syncthreads();
    #pragma unroll
    for (int d = 128; d > 0; d >>= 1) {
        if (t < d) s[t] += s[t + d];
        __syncthreads();
    }
    if (t == 0) bsum[blockIdx.x] = s[0];
}

// Pass 2: single block scans the block sums (nb <= 256).
__global__ __launch_bounds__(256) void scan_bsums_kernel(const int* __restrict__ bsum,
                                                         int* __restrict__ base, int nb,
                                                         int* __restrict__ off, int n) {
    __shared__ int s[256];
    int t = threadIdx.x;
    int v = (t < nb) ? bsum[t] : 0;
    s[t] = v;
    __syncthreads();
    #pragma unroll
    for (int d = 1; d < 256; d <<= 1) {
        int x = (t >= d) ? s[t - d] : 0;
        __syncthreads();
        s[t] += x;
        __syncthreads();
    }
    if (t < nb) base[t] = s[t] - v;   // exclusive prefix of block sums
    if (t == 255) off[n] = s[255];    // grand total
}

// Pass 3: per-chunk exclusive scan + base, write off & cur.
__global__ __launch_bounds__(256) void scatter_offsets_kernel(const int* __restrict__ deg,
                                                              const int* __restrict__ base,
                                                              int* __restrict__ off,
                                                              int* __restrict__ cur, int n) {
    __shared__ int s[256];
    int t = threadIdx.x;
    int i = blockIdx.x * 256 + t;
    int v = (i < n) ? deg[i] : 0;
    s[t] = v;
    __syncthreads();
    #pragma unroll
    for (int d = 1; d < 256; d <<= 1) {
        int x = (t >= d) ? s[t - d] : 0;
        __syncthreads();
        s[t] += x;
        __syncthreads();
    }
    if (i < n) {
        int excl = s[t] - v + base[blockIdx.x];
        off[i] = excl;
        cur[i] = excl;
    }
}

__global__ void fill_csr_kernel(const int* __restrict__ src, const int* __restrict__ dst,
                                int* __restrict__ cur, int* __restrict__ ssrc, int ne) {
    int e = blockIdx.x * blockDim.x + threadIdx.x;
    if (e < ne) {
        int p = atomicAdd(&cur[dst[e]], 1);
        ssrc[p] = src[e];
    }
}

// ---------------- dual GEMM:  S = A@Ws + b,  T = A@Wn ----------------
// A: [M][128] row-major. Ws,Wn: [128][dout]. Virtual B = [Ws|Wn] -> [128][2*dout].
// Tile: 64 rows x 64 cols, 256 threads, 4x4 micro-tile, BK=64.

#define BM 64
#define BN 64
#define BK 64
#define KDIM 128

__global__ __launch_bounds__(256) void gemm_dual_kernel(
    const float* __restrict__ A,
    const float* __restrict__ Ws, const float* __restrict__ Wn,
    const float* __restrict__ bias,
    float* __restrict__ S, float* __restrict__ T,
    int M, int dout)
{
    const int dout2 = 2 * dout;
    __shared__ float As[BK][BM + 4];  // transposed: As[k][m]; pad keeps float4 align, kills conflicts
    __shared__ float Bs[BK][BN];

    const int bm = blockIdx.x * BM;
    const int bn = blockIdx.y * BN;
    const int tid = threadIdx.x;
    const int tx = tid & 15;   // col group 0..15
    const int ty = tid >> 4;   // row group 0..15

    float acc[4][4] = {};

    for (int k0 = 0; k0 < KDIM; k0 += BK) {
        // stage A chunk: 64 rows x 64 k -> As[k][m]   (1024 float4, 4 per thread)
        #pragma unroll
        for (int i = 0; i < 4; ++i) {
            int idx = tid + i * 256;      // 0..1023
            int row = idx >> 4;           // 0..63
            int kq  = idx & 15;           // float4 index along k
            int grow = bm + row;
            float4 v = make_float4(0.f, 0.f, 0.f, 0.f);
            if (grow < M)
                v = *(const float4*)(A + (long)grow * KDIM + k0 + kq * 4);
            As[kq * 4 + 0][row] = v.x;
            As[kq * 4 + 1][row] = v.y;
            As[kq * 4 + 2][row] = v.z;
            As[kq * 4 + 3][row] = v.w;
        }
        // stage B chunk: Bs[kk][col] from [Ws|Wn]
        #pragma unroll
        for (int i = 0; i < 4; ++i) {
            int idx = tid + i * 256;
            int kk = idx >> 4;            // 0..63
            int cq = idx & 15;            // float4 col group
            int col = bn + cq * 4;
            int krow = k0 + kk;
            float4 v = make_float4(0.f, 0.f, 0.f, 0.f);
            if (col < dout) {
                v = *(const float4*)(Ws + (long)krow * dout + col);
            } else if (col < dout2) {
                v = *(const float4*)(Wn + (long)krow * dout + (col - dout));
            }
            *(float4*)&Bs[kk][cq * 4] = v;
        }
        __syncthreads();

        #pragma unroll
        for (int k = 0; k < BK; ++k) {
            float4 a4 = *(const float4*)&As[k][ty * 4];
            float4 b4 = *(const float4*)&Bs[k][tx * 4];
            float av[4] = {a4.x, a4.y, a4.z, a4.w};
            float bv[4] = {b4.x, b4.y, b4.z, b4.w};
            #pragma unroll
            for (int i = 0; i < 4; ++i)
                #pragma unroll
                for (int j = 0; j < 4; ++j)
                    acc[i][j] = fmaf(av[i], bv[j], acc[i][j]);
        }
        __syncthreads();
    }

    // epilogue
    #pragma unroll
    for (int i = 0; i < 4; ++i) {
        int grow = bm + ty * 4 + i;
        if (grow >= M) continue;
        #pragma unroll
        for (int j = 0; j < 4; ++j) {
            int col = bn + tx * 4 + j;
            if (col < dout) {
                S[(long)grow * dout + col] = acc[i][j] + bias[col];
            } else if (col < dout2) {
                T[(long)grow * dout + (col - dout)] = acc[i][j];
            }
        }
    }
}

// ---------------- aggregation: out[n] = act( S[n] + (sum_{e in in(n)} T[src_e]) / deg ) ----

template <int RELU>
__global__ void agg_kernel(const float* __restrict__ S, const float* __restrict__ T,
                           const int* __restrict__ off, const int* __restrict__ ssrc,
                           float* __restrict__ out, int dout)
{
    int n = blockIdx.x;
    int c = threadIdx.x;
    if (c >= dout) return;
    int a = off[n];
    int b = off[n + 1];
    float acc = 0.f;
    int i = a;
    for (; i + 3 < b; i += 4) {
        int s0 = ssrc[i], s1 = ssrc[i + 1], s2 = ssrc[i + 2], s3 = ssrc[i + 3];
        float v0 = T[(long)s0 * dout + c];
        float v1 = T[(long)s1 * dout + c];
        float v2 = T[(long)s2 * dout + c];
        float v3 = T[(long)s3 * dout + c];
        acc += (v0 + v1) + (v2 + v3);
    }
    for (; i < b; ++i) acc += T[(long)ssrc[i] * dout + c];
    int deg = b - a;
    float scale = (deg > 0) ? (1.0f / (float)deg) : 0.f;
    float v = S[(long)n * dout + c] + acc * scale;
    if (RELU) v = fmaxf(v, 0.f);
    out[(long)n * dout + c] = v;
}

// ---------------- launch ----------------

extern "C" void kernel_launch(void* const* d_in, const int* in_sizes, int n_in,
                              void* d_out, int out_size, void* d_ws, size_t ws_size,
                              hipStream_t stream) {
    const float* feat = (const float*)d_in[0];
    const int*   src  = (const int*)d_in[1];
    const int*   dst  = (const int*)d_in[2];
    const float* ws0  = (const float*)d_in[3];
    const float* wn0  = (const float*)d_in[4];
    const float* b0   = (const float*)d_in[5];
    const float* ws1  = (const float*)d_in[6];
    const float* wn1  = (const float*)d_in[7];
    const float* b1   = (const float*)d_in[8];
    const float* ws2  = (const float*)d_in[9];
    const float* wn2  = (const float*)d_in[10];
    const float* b2   = (const float*)d_in[11];

    const int N = N_NODES;
    const int NE = N_EDGES;
    const int NB = (N + 255) / 256;  // 196 scan blocks

    char* ws = (char*)d_ws;
    // workspace layout (256-aligned)
    int*   offsets = (int*)(ws + 0);            // 50001 ints
    int*   cursor  = (int*)(ws + 200704);       // 50000 ints
    int*   degi    = (int*)(ws + 401408);       // 50000 ints
    int*   bsum    = (int*)(ws + 601600);       // 196 ints (block sums)
    int*   bbase   = (int*)(ws + 602432);       // 196 ints (scanned bases)
    int*   ssrc    = (int*)(ws + 603648);       // 600000 ints
    float* hbuf    = (float*)(ws + 3003904);    // 50000*128 f32
    float* sbuf    = (float*)(ws + 28603904);   // 50000*128 f32
    float* tbuf    = (float*)(ws + 54203904);   // 50000*128 f32  (end ~79.8 MB)

    // ---- CSR build (graph identical every call; rebuilt per launch for capture-safety) ----
    hipMemsetAsync(degi, 0, (size_t)N * sizeof(int), stream);
    count_deg_kernel<<<(NE + 255) / 256, 256, 0, stream>>>(dst, degi, NE);
    block_sums_kernel<<<NB, 256, 0, stream>>>(degi, bsum, N);
    scan_bsums_kernel<<<1, 256, 0, stream>>>(bsum, bbase, NB, offsets, N);
    scatter_offsets_kernel<<<NB, 256, 0, stream>>>(degi, bbase, offsets, cursor, N);
    fill_csr_kernel<<<(NE + 255) / 256, 256, 0, stream>>>(src, dst, cursor, ssrc, NE);

    const int gx = (N + BM - 1) / BM;  // 782

    // ---- layer 0: feat -> hbuf (relu) ----
    gemm_dual_kernel<<<dim3(gx, 4), 256, 0, stream>>>(feat, ws0, wn0, b0, sbuf, tbuf, N, 128);
    agg_kernel<1><<<N, 128, 0, stream>>>(sbuf, tbuf, offsets, ssrc, hbuf, 128);

    // ---- layer 1: hbuf -> hbuf (relu) ----
    gemm_dual_kernel<<<dim3(gx, 4), 256, 0, stream>>>(hbuf, ws1, wn1, b1, sbuf, tbuf, N, 128);
    agg_kernel<1><<<N, 128, 0, stream>>>(sbuf, tbuf, offsets, ssrc, hbuf, 128);

    // ---- layer 2: hbuf -> d_out (no relu) ----
    gemm_dual_kernel<<<dim3(gx, 2), 256, 0, stream>>>(hbuf, ws2, wn2, b2, sbuf, tbuf, N, 40);
    agg_kernel<0><<<N, 64, 0, stream>>>(sbuf, tbuf, offsets, ssrc, (float*)d_out, 40);
}

// Round 3
// 374.190 us; speedup vs baseline: 1.4580x; 1.1961x over previous
//
#include <hip/hip_runtime.h>

#define N_NODES 50000
#define N_EDGES 600000

typedef short bf16x8 __attribute__((ext_vector_type(8)));
typedef float f32x4  __attribute__((ext_vector_type(4)));

// ---------------- bf16 split (RNE) ----------------
__device__ inline void split_bf16(float a, ushort& hi, ushort& lo) {
    union { float f; unsigned u; } v; v.f = a;
    unsigned r = (v.u + 0x7FFFu + ((v.u >> 16) & 1u)) >> 16;   // RNE to bf16
    hi = (ushort)r;
    union { unsigned u; float f; } hv; hv.u = r << 16;
    float res = a - hv.f;
    union { float f; unsigned u; } w; w.f = res;
    unsigned r2 = (w.u + 0x7FFFu + ((w.u >> 16) & 1u)) >> 16;
    lo = (ushort)r2;
}

// ---------------- CSR build ----------------

__global__ void count_deg_kernel(const int* __restrict__ dst, int* __restrict__ deg, int ne) {
    int e = blockIdx.x * blockDim.x + threadIdx.x;
    if (e < ne) atomicAdd(&deg[dst[e]], 1);
}

__global__ __launch_bounds__(256) void block_sums_kernel(const int* __restrict__ deg,
                                                         int* __restrict__ bsum, int n) {
    __shared__ int s[256];
    int t = threadIdx.x;
    int i = blockIdx.x * 256 + t;
    s[t] = (i < n) ? deg[i] : 0;
    __syncthreads();
    #pragma unroll
    for (int d = 128; d > 0; d >>= 1) {
        if (t < d) s[t] += s[t + d];
        __syncthreads();
    }
    if (t == 0) bsum[blockIdx.x] = s[0];
}

__global__ __launch_bounds__(256) void scan_bsums_kernel(const int* __restrict__ bsum,
                                                         int* __restrict__ base, int nb,
                                                         int* __restrict__ off, int n) {
    __shared__ int s[256];
    int t = threadIdx.x;
    int v = (t < nb) ? bsum[t] : 0;
    s[t] = v;
    __syncthreads();
    #pragma unroll
    for (int d = 1; d < 256; d <<= 1) {
        int x = (t >= d) ? s[t - d] : 0;
        __syncthreads();
        s[t] += x;
        __syncthreads();
    }
    if (t < nb) base[t] = s[t] - v;
    if (t == 255) off[n] = s[255];
}

__global__ __launch_bounds__(256) void scatter_offsets_kernel(const int* __restrict__ deg,
                                                              const int* __restrict__ base,
                                                              int* __restrict__ off,
                                                              int* __restrict__ cur, int n) {
    __shared__ int s[256];
    int t = threadIdx.x;
    int i = blockIdx.x * 256 + t;
    int v = (i < n) ? deg[i] : 0;
    s[t] = v;
    __syncthreads();
    #pragma unroll
    for (int d = 1; d < 256; d <<= 1) {
        int x = (t >= d) ? s[t - d] : 0;
        __syncthreads();
        s[t] += x;
        __syncthreads();
    }
    if (i < n) {
        int excl = s[t] - v + base[blockIdx.x];
        off[i] = excl;
        cur[i] = excl;
    }
}

__global__ void fill_csr_kernel(const int* __restrict__ src, const int* __restrict__ dst,
                                int* __restrict__ cur, int* __restrict__ ssrc, int ne) {
    int e = blockIdx.x * blockDim.x + threadIdx.x;
    if (e < ne) {
        int p = atomicAdd(&cur[dst[e]], 1);
        ssrc[p] = src[e];
    }
}

// ---------------- weight pre-convert: Bt[n][k] = [Ws|Wn]^T, bf16 hi/lo ----------------
// grid = 2*dout blocks, 128 threads (k)
__global__ void convert_w_kernel(const float* __restrict__ Ws, const float* __restrict__ Wn,
                                 int dout, ushort* __restrict__ Bth, ushort* __restrict__ Btl) {
    int n = blockIdx.x;
    int k = threadIdx.x;
    float w = (n < dout) ? Ws[(long)k * dout + n] : Wn[(long)k * dout + (n - dout)];
    ushort hi, lo;
    split_bf16(w, hi, lo);
    Bth[n * 128 + k] = hi;
    Btl[n * 128 + k] = lo;
}

// ---------------- split-bf16 MFMA dual GEMM ----------------
// A: [M][128] fp32.  Bt_{hi,lo}: [NCOL][128] bf16 (NCOL = 2*dout).
// S = A@Ws + bias (cols 0..dout), T = A@Wn (cols dout..2dout).
// Block: 64 rows (A staged in LDS as hi/lo bf16), 256 threads = 4 waves.
// mfma_f32_16x16x32_bf16: A-frag lane: A[m=lane&15][k=quad*8+j]; B-frag: B[k=quad*8+j][n=lane&15];
// C/D: col=lane&15, row=quad*4+reg.

#define KDIM 128
#define BKC  32
#define APAD 40   // halfs per staged row (32 + 8): 80B stride -> <=2-way bank aliasing (free)

__device__ inline void stage_a_tile(const float* __restrict__ A, int bm, int M, int k0,
                                    ushort* __restrict__ Ahi, ushort* __restrict__ Alo, int tid) {
    int m  = tid >> 2;
    int kq = (tid & 3) * 8;
    int grow = bm + m;
    float f[8];
    if (grow < M) {
        const float* ap = A + (long)grow * KDIM + k0 + kq;
        float4 a0 = *(const float4*)ap;
        float4 a1 = *(const float4*)(ap + 4);
        f[0] = a0.x; f[1] = a0.y; f[2] = a0.z; f[3] = a0.w;
        f[4] = a1.x; f[5] = a1.y; f[6] = a1.z; f[7] = a1.w;
    } else {
        #pragma unroll
        for (int i = 0; i < 8; ++i) f[i] = 0.f;
    }
    ushort h[8], l[8];
    #pragma unroll
    for (int i = 0; i < 8; ++i) split_bf16(f[i], h[i], l[i]);
    uint4 hw, lw;
    hw.x = (unsigned)h[0] | ((unsigned)h[1] << 16);
    hw.y = (unsigned)h[2] | ((unsigned)h[3] << 16);
    hw.z = (unsigned)h[4] | ((unsigned)h[5] << 16);
    hw.w = (unsigned)h[6] | ((unsigned)h[7] << 16);
    lw.x = (unsigned)l[0] | ((unsigned)l[1] << 16);
    lw.y = (unsigned)l[2] | ((unsigned)l[3] << 16);
    lw.z = (unsigned)l[4] | ((unsigned)l[5] << 16);
    lw.w = (unsigned)l[6] | ((unsigned)l[7] << 16);
    *(uint4*)&Ahi[m * APAD + kq] = hw;
    *(uint4*)&Alo[m * APAD + kq] = lw;
}

// Layers 0/1: dout=128, NCOL=256. Wave w -> cols [64w,64w+64), rows bm..bm+64.
__global__ __launch_bounds__(256) void gemm_mfma_wide(
    const float* __restrict__ A,
    const ushort* __restrict__ Bth, const ushort* __restrict__ Btl,
    const float* __restrict__ bias,
    float* __restrict__ S, float* __restrict__ T, int M)
{
    __shared__ ushort Ahi[64 * APAD];
    __shared__ ushort Alo[64 * APAD];

    const int tid = threadIdx.x;
    const int bm = blockIdx.x * 64;
    const int wave = tid >> 6;
    const int lane = tid & 63;
    const int lane16 = lane & 15;
    const int quad = lane >> 4;
    const int colbase = wave * 64;

    f32x4 acc[4][4] = {};   // [row tile][col tile]

    for (int c = 0; c < 4; ++c) {
        int k0 = c * BKC;
        __syncthreads();
        stage_a_tile(A, bm, M, k0, Ahi, Alo, tid);
        __syncthreads();

        bf16x8 ah[4], al[4];
        #pragma unroll
        for (int r = 0; r < 4; ++r) {
            int off = (16 * r + lane16) * APAD + quad * 8;
            ah[r] = *(const bf16x8*)&Ahi[off];
            al[r] = *(const bf16x8*)&Alo[off];
        }
        #pragma unroll
        for (int ct = 0; ct < 4; ++ct) {
            int col = colbase + 16 * ct + lane16;
            long boff = (long)col * KDIM + k0 + quad * 8;
            bf16x8 bh = *(const bf16x8*)(Bth + boff);
            bf16x8 bl = *(const bf16x8*)(Btl + boff);
            #pragma unroll
            for (int r = 0; r < 4; ++r) {
                acc[r][ct] = __builtin_amdgcn_mfma_f32_16x16x32_bf16(ah[r], bh, acc[r][ct], 0, 0, 0);
                acc[r][ct] = __builtin_amdgcn_mfma_f32_16x16x32_bf16(ah[r], bl, acc[r][ct], 0, 0, 0);
                acc[r][ct] = __builtin_amdgcn_mfma_f32_16x16x32_bf16(al[r], bh, acc[r][ct], 0, 0, 0);
            }
        }
    }

    // epilogue: cols<128 -> S+bias, else T
    #pragma unroll
    for (int ct = 0; ct < 4; ++ct) {
        int col = colbase + 16 * ct + lane16;
        bool toS = col < 128;
        float bv = toS ? bias[col] : 0.f;
        int tcol = toS ? col : col - 128;
        #pragma unroll
        for (int r = 0; r < 4; ++r) {
            #pragma unroll
            for (int i = 0; i < 4; ++i) {
                int row = bm + 16 * r + quad * 4 + i;
                if (row < M) {
                    if (toS) S[(long)row * 128 + tcol] = acc[r][ct][i] + bv;
                    else     T[(long)row * 128 + tcol] = acc[r][ct][i];
                }
            }
        }
    }
}

// Layer 2: dout=40, NCOL=80. Wave w -> rows bm+16w..+16, all 80 cols (5 col tiles).
__global__ __launch_bounds__(256) void gemm_mfma_narrow(
    const float* __restrict__ A,
    const ushort* __restrict__ Bth, const ushort* __restrict__ Btl,
    const float* __restrict__ bias,
    float* __restrict__ S, float* __restrict__ T, int M)
{
    __shared__ ushort Ahi[64 * APAD];
    __shared__ ushort Alo[64 * APAD];

    const int tid = threadIdx.x;
    const int bm = blockIdx.x * 64;
    const int wave = tid >> 6;
    const int lane = tid & 63;
    const int lane16 = lane & 15;
    const int quad = lane >> 4;

    f32x4 acc[5] = {};

    for (int c = 0; c < 4; ++c) {
        int k0 = c * BKC;
        __syncthreads();
        stage_a_tile(A, bm, M, k0, Ahi, Alo, tid);
        __syncthreads();

        int aoff = (16 * wave + lane16) * APAD + quad * 8;
        bf16x8 ah = *(const bf16x8*)&Ahi[aoff];
        bf16x8 al = *(const bf16x8*)&Alo[aoff];
        #pragma unroll
        for (int ct = 0; ct < 5; ++ct) {
            int col = 16 * ct + lane16;
            long boff = (long)col * KDIM + k0 + quad * 8;
            bf16x8 bh = *(const bf16x8*)(Bth + boff);
            bf16x8 bl = *(const bf16x8*)(Btl + boff);
            acc[ct] = __builtin_amdgcn_mfma_f32_16x16x32_bf16(ah, bh, acc[ct], 0, 0, 0);
            acc[ct] = __builtin_amdgcn_mfma_f32_16x16x32_bf16(ah, bl, acc[ct], 0, 0, 0);
            acc[ct] = __builtin_amdgcn_mfma_f32_16x16x32_bf16(al, bh, acc[ct], 0, 0, 0);
        }
    }

    #pragma unroll
    for (int ct = 0; ct < 5; ++ct) {
        int col = 16 * ct + lane16;
        bool toS = col < 40;
        float bv = toS ? bias[col] : 0.f;
        int tcol = toS ? col : col - 40;
        #pragma unroll
        for (int i = 0; i < 4; ++i) {
            int row = bm + 16 * wave + quad * 4 + i;
            if (row < M) {
                if (toS) S[(long)row * 40 + tcol] = acc[ct][i] + bv;
                else     T[(long)row * 40 + tcol] = acc[ct][i];
            }
        }
    }
}

// ---------------- aggregation: out[n] = act( S[n] + (sum_{e in in(n)} T[src_e]) / deg ) ----

template <int RELU>
__global__ void agg_kernel(const float* __restrict__ S, const float* __restrict__ T,
                           const int* __restrict__ off, const int* __restrict__ ssrc,
                           float* __restrict__ out, int dout)
{
    int n = blockIdx.x;
    int c = threadIdx.x;
    if (c >= dout) return;
    int a = off[n];
    int b = off[n + 1];
    float acc = 0.f;
    int i = a;
    for (; i + 3 < b; i += 4) {
        int s0 = ssrc[i], s1 = ssrc[i + 1], s2 = ssrc[i + 2], s3 = ssrc[i + 3];
        float v0 = T[(long)s0 * dout + c];
        float v1 = T[(long)s1 * dout + c];
        float v2 = T[(long)s2 * dout + c];
        float v3 = T[(long)s3 * dout + c];
        acc += (v0 + v1) + (v2 + v3);
    }
    for (; i < b; ++i) acc += T[(long)ssrc[i] * dout + c];
    int deg = b - a;
    float scale = (deg > 0) ? (1.0f / (float)deg) : 0.f;
    float v = S[(long)n * dout + c] + acc * scale;
    if (RELU) v = fmaxf(v, 0.f);
    out[(long)n * dout + c] = v;
}

// ---------------- launch ----------------

extern "C" void kernel_launch(void* const* d_in, const int* in_sizes, int n_in,
                              void* d_out, int out_size, void* d_ws, size_t ws_size,
                              hipStream_t stream) {
    const float* feat = (const float*)d_in[0];
    const int*   src  = (const int*)d_in[1];
    const int*   dst  = (const int*)d_in[2];
    const float* ws0  = (const float*)d_in[3];
    const float* wn0  = (const float*)d_in[4];
    const float* b0   = (const float*)d_in[5];
    const float* ws1  = (const float*)d_in[6];
    const float* wn1  = (const float*)d_in[7];
    const float* b1   = (const float*)d_in[8];
    const float* ws2  = (const float*)d_in[9];
    const float* wn2  = (const float*)d_in[10];
    const float* b2   = (const float*)d_in[11];

    const int N = N_NODES;
    const int NE = N_EDGES;
    const int NB = (N + 255) / 256;  // 196

    char* ws = (char*)d_ws;
    int*   offsets = (int*)(ws + 0);          // 50001 ints (live whole launch)
    int*   cursor  = (int*)(ws + 200704);     // 200000 B (dead after fill_csr)
    int*   degi    = (int*)(ws + 401408);     // 200000 B (dead after scatter)
    int*   bsum    = (int*)(ws + 601600);
    int*   bbase   = (int*)(ws + 602432);
    int*   ssrc    = (int*)(ws + 603648);     // 2400000 B (live whole launch)
    // Bt buffers overlap cursor/degi region — written only AFTER CSR build completes.
    ushort* Bth0 = (ushort*)(ws + 200704);    // 65536 B
    ushort* Btl0 = (ushort*)(ws + 266240);
    ushort* Bth1 = (ushort*)(ws + 331776);
    ushort* Btl1 = (ushort*)(ws + 397312);
    ushort* Bth2 = (ushort*)(ws + 462848);    // 20480 B
    ushort* Btl2 = (ushort*)(ws + 483328);    // end 503808 < 601600 OK
    float* hbuf = (float*)(ws + 3003904);     // 50000*128 f32
    float* sbuf = (float*)(ws + 28603904);
    float* tbuf = (float*)(ws + 54203904);    // end ~79.8 MB

    // ---- CSR build ----
    hipMemsetAsync(degi, 0, (size_t)N * sizeof(int), stream);
    count_deg_kernel<<<(NE + 255) / 256, 256, 0, stream>>>(dst, degi, NE);
    block_sums_kernel<<<NB, 256, 0, stream>>>(degi, bsum, N);
    scan_bsums_kernel<<<1, 256, 0, stream>>>(bsum, bbase, NB, offsets, N);
    scatter_offsets_kernel<<<NB, 256, 0, stream>>>(degi, bbase, offsets, cursor, N);
    fill_csr_kernel<<<(NE + 255) / 256, 256, 0, stream>>>(src, dst, cursor, ssrc, NE);

    // ---- weight pre-convert (after CSR: overlaps cursor/degi memory) ----
    convert_w_kernel<<<256, 128, 0, stream>>>(ws0, wn0, 128, Bth0, Btl0);
    convert_w_kernel<<<256, 128, 0, stream>>>(ws1, wn1, 128, Bth1, Btl1);
    convert_w_kernel<<<80, 128, 0, stream>>>(ws2, wn2, 40, Bth2, Btl2);

    const int gx = (N + 63) / 64;  // 782

    // ---- layer 0 ----
    gemm_mfma_wide<<<gx, 256, 0, stream>>>(feat, Bth0, Btl0, b0, sbuf, tbuf, N);
    agg_kernel<1><<<N, 128, 0, stream>>>(sbuf, tbuf, offsets, ssrc, hbuf, 128);

    // ---- layer 1 ----
    gemm_mfma_wide<<<gx, 256, 0, stream>>>(hbuf, Bth1, Btl1, b1, sbuf, tbuf, N);
    agg_kernel<1><<<N, 128, 0, stream>>>(sbuf, tbuf, offsets, ssrc, hbuf, 128);

    // ---- layer 2 ----
    gemm_mfma_narrow<<<gx, 256, 0, stream>>>(hbuf, Bth2, Btl2, b2, sbuf, tbuf, N);
    agg_kernel<0><<<N, 64, 0, stream>>>(sbuf, tbuf, offsets, ssrc, (float*)d_out, 40);
}

// Round 4
// 372.133 us; speedup vs baseline: 1.4661x; 1.0055x over previous
//
#include <hip/hip_runtime.h>

#define N_NODES 50000
#define N_EDGES 600000

typedef short bf16x8 __attribute__((ext_vector_type(8)));
typedef float f32x4  __attribute__((ext_vector_type(4)));

// ---------------- bf16 split (RNE) ----------------
__device__ inline void split_bf16(float a, ushort& hi, ushort& lo) {
    union { float f; unsigned u; } v; v.f = a;
    unsigned r = (v.u + 0x7FFFu + ((v.u >> 16) & 1u)) >> 16;   // RNE to bf16
    hi = (ushort)r;
    union { unsigned u; float f; } hv; hv.u = r << 16;
    float res = a - hv.f;
    union { float f; unsigned u; } w; w.f = res;
    unsigned r2 = (w.u + 0x7FFFu + ((w.u >> 16) & 1u)) >> 16;
    lo = (ushort)r2;
}

// ---------------- CSR build ----------------

__global__ void count_deg_kernel(const int* __restrict__ dst, int* __restrict__ deg, int ne) {
    int e = blockIdx.x * blockDim.x + threadIdx.x;
    if (e < ne) atomicAdd(&deg[dst[e]], 1);
}

__global__ __launch_bounds__(256) void block_sums_kernel(const int* __restrict__ deg,
                                                         int* __restrict__ bsum, int n) {
    __shared__ int s[256];
    int t = threadIdx.x;
    int i = blockIdx.x * 256 + t;
    s[t] = (i < n) ? deg[i] : 0;
    __syncthreads();
    #pragma unroll
    for (int d = 128; d > 0; d >>= 1) {
        if (t < d) s[t] += s[t + d];
        __syncthreads();
    }
    if (t == 0) bsum[blockIdx.x] = s[0];
}

__global__ __launch_bounds__(256) void scan_bsums_kernel(const int* __restrict__ bsum,
                                                         int* __restrict__ base, int nb,
                                                         int* __restrict__ off, int n) {
    __shared__ int s[256];
    int t = threadIdx.x;
    int v = (t < nb) ? bsum[t] : 0;
    s[t] = v;
    __syncthreads();
    #pragma unroll
    for (int d = 1; d < 256; d <<= 1) {
        int x = (t >= d) ? s[t - d] : 0;
        __syncthreads();
        s[t] += x;
        __syncthreads();
    }
    if (t < nb) base[t] = s[t] - v;
    if (t == 255) off[n] = s[255];
}

__global__ __launch_bounds__(256) void scatter_offsets_kernel(const int* __restrict__ deg,
                                                              const int* __restrict__ base,
                                                              int* __restrict__ off,
                                                              int* __restrict__ cur, int n) {
    __shared__ int s[256];
    int t = threadIdx.x;
    int i = blockIdx.x * 256 + t;
    int v = (i < n) ? deg[i] : 0;
    s[t] = v;
    __syncthreads();
    #pragma unroll
    for (int d = 1; d < 256; d <<= 1) {
        int x = (t >= d) ? s[t - d] : 0;
        __syncthreads();
        s[t] += x;
        __syncthreads();
    }
    if (i < n) {
        int excl = s[t] - v + base[blockIdx.x];
        off[i] = excl;
        cur[i] = excl;
    }
}

__global__ void fill_csr_kernel(const int* __restrict__ src, const int* __restrict__ dst,
                                int* __restrict__ cur, int* __restrict__ ssrc, int ne) {
    int e = blockIdx.x * blockDim.x + threadIdx.x;
    if (e < ne) {
        int p = atomicAdd(&cur[dst[e]], 1);
        ssrc[p] = src[e];
    }
}

// ---------------- weight pre-convert ----------------
__global__ void convert_w_kernel(const float* __restrict__ Ws, const float* __restrict__ Wn,
                                 int dout, ushort* __restrict__ Bth, ushort* __restrict__ Btl) {
    int n = blockIdx.x;
    int k = threadIdx.x;
    float w = (n < dout) ? Ws[(long)k * dout + n] : Wn[(long)k * dout + (n - dout)];
    ushort hi, lo;
    split_bf16(w, hi, lo);
    Bth[n * 128 + k] = hi;
    Btl[n * 128 + k] = lo;
}

// ---------------- split-bf16 MFMA dual GEMM ----------------

#define KDIM 128
#define BKC  32
#define APAD 40

__device__ inline void stage_a_tile(const float* __restrict__ A, int bm, int M, int k0,
                                    ushort* __restrict__ Ahi, ushort* __restrict__ Alo, int tid) {
    int m  = tid >> 2;
    int kq = (tid & 3) * 8;
    int grow = bm + m;
    float f[8];
    if (grow < M) {
        const float* ap = A + (long)grow * KDIM + k0 + kq;
        float4 a0 = *(const float4*)ap;
        float4 a1 = *(const float4*)(ap + 4);
        f[0] = a0.x; f[1] = a0.y; f[2] = a0.z; f[3] = a0.w;
        f[4] = a1.x; f[5] = a1.y; f[6] = a1.z; f[7] = a1.w;
    } else {
        #pragma unroll
        for (int i = 0; i < 8; ++i) f[i] = 0.f;
    }
    ushort h[8], l[8];
    #pragma unroll
    for (int i = 0; i < 8; ++i) split_bf16(f[i], h[i], l[i]);
    uint4 hw, lw;
    hw.x = (unsigned)h[0] | ((unsigned)h[1] << 16);
    hw.y = (unsigned)h[2] | ((unsigned)h[3] << 16);
    hw.z = (unsigned)h[4] | ((unsigned)h[5] << 16);
    hw.w = (unsigned)h[6] | ((unsigned)h[7] << 16);
    lw.x = (unsigned)l[0] | ((unsigned)l[1] << 16);
    lw.y = (unsigned)l[2] | ((unsigned)l[3] << 16);
    lw.z = (unsigned)l[4] | ((unsigned)l[5] << 16);
    lw.w = (unsigned)l[6] | ((unsigned)l[7] << 16);
    *(uint4*)&Ahi[m * APAD + kq] = hw;
    *(uint4*)&Alo[m * APAD + kq] = lw;
}

__global__ __launch_bounds__(256) void gemm_mfma_wide(
    const float* __restrict__ A,
    const ushort* __restrict__ Bth, const ushort* __restrict__ Btl,
    const float* __restrict__ bias,
    float* __restrict__ S, float* __restrict__ T, int M)
{
    __shared__ ushort Ahi[64 * APAD];
    __shared__ ushort Alo[64 * APAD];

    const int tid = threadIdx.x;
    const int bm = blockIdx.x * 64;
    const int wave = tid >> 6;
    const int lane = tid & 63;
    const int lane16 = lane & 15;
    const int quad = lane >> 4;
    const int colbase = wave * 64;

    f32x4 acc[4][4] = {};

    for (int c = 0; c < 4; ++c) {
        int k0 = c * BKC;
        __syncthreads();
        stage_a_tile(A, bm, M, k0, Ahi, Alo, tid);
        __syncthreads();

        bf16x8 ah[4], al[4];
        #pragma unroll
        for (int r = 0; r < 4; ++r) {
            int off = (16 * r + lane16) * APAD + quad * 8;
            ah[r] = *(const bf16x8*)&Ahi[off];
            al[r] = *(const bf16x8*)&Alo[off];
        }
        #pragma unroll
        for (int ct = 0; ct < 4; ++ct) {
            int col = colbase + 16 * ct + lane16;
            long boff = (long)col * KDIM + k0 + quad * 8;
            bf16x8 bh = *(const bf16x8*)(Bth + boff);
            bf16x8 bl = *(const bf16x8*)(Btl + boff);
            #pragma unroll
            for (int r = 0; r < 4; ++r) {
                acc[r][ct] = __builtin_amdgcn_mfma_f32_16x16x32_bf16(ah[r], bh, acc[r][ct], 0, 0, 0);
                acc[r][ct] = __builtin_amdgcn_mfma_f32_16x16x32_bf16(ah[r], bl, acc[r][ct], 0, 0, 0);
                acc[r][ct] = __builtin_amdgcn_mfma_f32_16x16x32_bf16(al[r], bh, acc[r][ct], 0, 0, 0);
            }
        }
    }

    #pragma unroll
    for (int ct = 0; ct < 4; ++ct) {
        int col = colbase + 16 * ct + lane16;
        bool toS = col < 128;
        float bv = toS ? bias[col] : 0.f;
        int tcol = toS ? col : col - 128;
        #pragma unroll
        for (int r = 0; r < 4; ++r) {
            #pragma unroll
            for (int i = 0; i < 4; ++i) {
                int row = bm + 16 * r + quad * 4 + i;
                if (row < M) {
                    if (toS) S[(long)row * 128 + tcol] = acc[r][ct][i] + bv;
                    else     T[(long)row * 128 + tcol] = acc[r][ct][i];
                }
            }
        }
    }
}

__global__ __launch_bounds__(256) void gemm_mfma_narrow(
    const float* __restrict__ A,
    const ushort* __restrict__ Bth, const ushort* __restrict__ Btl,
    const float* __restrict__ bias,
    float* __restrict__ S, float* __restrict__ T, int M)
{
    __shared__ ushort Ahi[64 * APAD];
    __shared__ ushort Alo[64 * APAD];

    const int tid = threadIdx.x;
    const int bm = blockIdx.x * 64;
    const int wave = tid >> 6;
    const int lane = tid & 63;
    const int lane16 = lane & 15;
    const int quad = lane >> 4;

    f32x4 acc[5] = {};

    for (int c = 0; c < 4; ++c) {
        int k0 = c * BKC;
        __syncthreads();
        stage_a_tile(A, bm, M, k0, Ahi, Alo, tid);
        __syncthreads();

        int aoff = (16 * wave + lane16) * APAD + quad * 8;
        bf16x8 ah = *(const bf16x8*)&Ahi[aoff];
        bf16x8 al = *(const bf16x8*)&Alo[aoff];
        #pragma unroll
        for (int ct = 0; ct < 5; ++ct) {
            int col = 16 * ct + lane16;
            long boff = (long)col * KDIM + k0 + quad * 8;
            bf16x8 bh = *(const bf16x8*)(Bth + boff);
            bf16x8 bl = *(const bf16x8*)(Btl + boff);
            acc[ct] = __builtin_amdgcn_mfma_f32_16x16x32_bf16(ah, bh, acc[ct], 0, 0, 0);
            acc[ct] = __builtin_amdgcn_mfma_f32_16x16x32_bf16(ah, bl, acc[ct], 0, 0, 0);
            acc[ct] = __builtin_amdgcn_mfma_f32_16x16x32_bf16(al, bh, acc[ct], 0, 0, 0);
        }
    }

    #pragma unroll
    for (int ct = 0; ct < 5; ++ct) {
        int col = 16 * ct + lane16;
        bool toS = col < 40;
        float bv = toS ? bias[col] : 0.f;
        int tcol = toS ? col : col - 40;
        #pragma unroll
        for (int i = 0; i < 4; ++i) {
            int row = bm + 16 * wave + quad * 4 + i;
            if (row < M) {
                if (toS) S[(long)row * 40 + tcol] = acc[ct][i] + bv;
                else     T[(long)row * 40 + tcol] = acc[ct][i];
            }
        }
    }
}

// ---------------- aggregation, wave-per-node ----------------
// dout=128: lane covers features 4*(lane&31).., edge slot = lane>>5 (2 edges/instr).
// 4 unrolled chunks -> 8 edges in flight per wave.

template <int RELU>
__global__ __launch_bounds__(256) void agg128_kernel(
    const float* __restrict__ S, const float* __restrict__ T,
    const int* __restrict__ off, const int* __restrict__ ssrc,
    float* __restrict__ out, int nnodes)
{
    const int node = (blockIdx.x * 256 + threadIdx.x) >> 6;
    if (node >= nnodes) return;
    const int lane = threadIdx.x & 63;
    const int slot = lane >> 5;          // 0..1
    const int fo = (lane & 31) * 4;      // feature offset

    const int a = off[node];
    const int b = off[node + 1];

    f32x4 acc0 = {0,0,0,0}, acc1 = {0,0,0,0}, acc2 = {0,0,0,0}, acc3 = {0,0,0,0};

    int i = a;
    for (; i + 8 <= b; i += 8) {
        int s0 = ssrc[i + 0 + slot];
        int s1 = ssrc[i + 2 + slot];
        int s2 = ssrc[i + 4 + slot];
        int s3 = ssrc[i + 6 + slot];
        f32x4 v0 = *(const f32x4*)(T + (long)s0 * 128 + fo);
        f32x4 v1 = *(const f32x4*)(T + (long)s1 * 128 + fo);
        f32x4 v2 = *(const f32x4*)(T + (long)s2 * 128 + fo);
        f32x4 v3 = *(const f32x4*)(T + (long)s3 * 128 + fo);
        acc0 += v0; acc1 += v1; acc2 += v2; acc3 += v3;
    }
    for (; i < b; i += 2) {
        int e = i + slot;
        if (e < b) {
            int s = ssrc[e];
            acc0 += *(const f32x4*)(T + (long)s * 128 + fo);
        }
    }
    f32x4 acc = (acc0 + acc1) + (acc2 + acc3);

    // reduce across the 2 slots (lane ^ 32)
    f32x4 other;
    other[0] = __shfl_xor((float)acc[0], 32);
    other[1] = __shfl_xor((float)acc[1], 32);
    other[2] = __shfl_xor((float)acc[2], 32);
    other[3] = __shfl_xor((float)acc[3], 32);
    acc += other;

    if (slot == 0) {
        int deg = b - a;
        float scale = (deg > 0) ? (1.0f / (float)deg) : 0.f;
        f32x4 s4 = *(const f32x4*)(S + (long)node * 128 + fo);
        f32x4 r = s4 + acc * scale;
        if (RELU) {
            r[0] = fmaxf(r[0], 0.f); r[1] = fmaxf(r[1], 0.f);
            r[2] = fmaxf(r[2], 0.f); r[3] = fmaxf(r[3], 0.f);
        }
        *(f32x4*)(out + (long)node * 128 + fo) = r;
    }
}

// dout=40: lanes 0..59 active; slot = lane/10 (6 edges/instr), feature = 4*(lane%10).
template <int RELU>
__global__ __launch_bounds__(256) void agg40_kernel(
    const float* __restrict__ S, const float* __restrict__ T,
    const int* __restrict__ off, const int* __restrict__ ssrc,
    float* __restrict__ out, int nnodes)
{
    const int node = (blockIdx.x * 256 + threadIdx.x) >> 6;
    if (node >= nnodes) return;
    const int lane = threadIdx.x & 63;
    const bool active = lane < 60;
    const int slot = active ? (lane / 10) : 5;   // 0..5
    const int fi = lane % 10;
    const int fo = fi * 4;

    const int a = off[node];
    const int b = off[node + 1];

    f32x4 acc0 = {0,0,0,0}, acc1 = {0,0,0,0};

    int i = a;
    for (; i + 12 <= b; i += 12) {
        int s0 = ssrc[i + slot];
        int s1 = ssrc[i + 6 + slot];
        f32x4 v0 = *(const f32x4*)(T + (long)s0 * 40 + fo);
        f32x4 v1 = *(const f32x4*)(T + (long)s1 * 40 + fo);
        if (active) { acc0 += v0; acc1 += v1; }
    }
    for (; i < b; i += 6) {
        int e = i + slot;
        if (active && e < b) {
            int s = ssrc[e];
            acc0 += *(const f32x4*)(T + (long)s * 40 + fo);
        }
    }
    f32x4 acc = acc0 + acc1;

    // reduce slots 1..5 into slot 0 (lanes 0..9)
    f32x4 tot = acc;
    #pragma unroll
    for (int d = 10; d <= 50; d += 10) {
        int srcl = fi + d;
        tot[0] += __shfl((float)acc[0], srcl);
        tot[1] += __shfl((float)acc[1], srcl);
        tot[2] += __shfl((float)acc[2], srcl);
        tot[3] += __shfl((float)acc[3], srcl);
    }

    if (lane < 10) {
        int deg = b - a;
        float scale = (deg > 0) ? (1.0f / (float)deg) : 0.f;
        f32x4 s4 = *(const f32x4*)(S + (long)node * 40 + fo);
        f32x4 r = s4 + tot * scale;
        if (RELU) {
            r[0] = fmaxf(r[0], 0.f); r[1] = fmaxf(r[1], 0.f);
            r[2] = fmaxf(r[2], 0.f); r[3] = fmaxf(r[3], 0.f);
        }
        *(f32x4*)(out + (long)node * 40 + fo) = r;
    }
}

// ---------------- launch ----------------

extern "C" void kernel_launch(void* const* d_in, const int* in_sizes, int n_in,
                              void* d_out, int out_size, void* d_ws, size_t ws_size,
                              hipStream_t stream) {
    const float* feat = (const float*)d_in[0];
    const int*   src  = (const int*)d_in[1];
    const int*   dst  = (const int*)d_in[2];
    const float* ws0  = (const float*)d_in[3];
    const float* wn0  = (const float*)d_in[4];
    const float* b0   = (const float*)d_in[5];
    const float* ws1  = (const float*)d_in[6];
    const float* wn1  = (const float*)d_in[7];
    const float* b1   = (const float*)d_in[8];
    const float* ws2  = (const float*)d_in[9];
    const float* wn2  = (const float*)d_in[10];
    const float* b2   = (const float*)d_in[11];

    const int N = N_NODES;
    const int NE = N_EDGES;
    const int NB = (N + 255) / 256;  // 196

    char* ws = (char*)d_ws;
    int*   offsets = (int*)(ws + 0);
    int*   cursor  = (int*)(ws + 200704);
    int*   degi    = (int*)(ws + 401408);
    int*   bsum    = (int*)(ws + 601600);
    int*   bbase   = (int*)(ws + 602432);
    int*   ssrc    = (int*)(ws + 603648);
    ushort* Bth0 = (ushort*)(ws + 200704);   // overlaps cursor/degi, written after CSR build
    ushort* Btl0 = (ushort*)(ws + 266240);
    ushort* Bth1 = (ushort*)(ws + 331776);
    ushort* Btl1 = (ushort*)(ws + 397312);
    ushort* Bth2 = (ushort*)(ws + 462848);
    ushort* Btl2 = (ushort*)(ws + 483328);
    float* hbuf = (float*)(ws + 3003904);
    float* sbuf = (float*)(ws + 28603904);
    float* tbuf = (float*)(ws + 54203904);

    // ---- CSR build ----
    hipMemsetAsync(degi, 0, (size_t)N * sizeof(int), stream);
    count_deg_kernel<<<(NE + 255) / 256, 256, 0, stream>>>(dst, degi, NE);
    block_sums_kernel<<<NB, 256, 0, stream>>>(degi, bsum, N);
    scan_bsums_kernel<<<1, 256, 0, stream>>>(bsum, bbase, NB, offsets, N);
    scatter_offsets_kernel<<<NB, 256, 0, stream>>>(degi, bbase, offsets, cursor, N);
    fill_csr_kernel<<<(NE + 255) / 256, 256, 0, stream>>>(src, dst, cursor, ssrc, NE);

    // ---- weight pre-convert ----
    convert_w_kernel<<<256, 128, 0, stream>>>(ws0, wn0, 128, Bth0, Btl0);
    convert_w_kernel<<<256, 128, 0, stream>>>(ws1, wn1, 128, Bth1, Btl1);
    convert_w_kernel<<<80, 128, 0, stream>>>(ws2, wn2, 40, Bth2, Btl2);

    const int gx = (N + 63) / 64;        // 782 GEMM blocks
    const int ga = (N + 3) / 4;          // 12500 agg blocks (4 waves/block)

    // ---- layer 0 ----
    gemm_mfma_wide<<<gx, 256, 0, stream>>>(feat, Bth0, Btl0, b0, sbuf, tbuf, N);
    agg128_kernel<1><<<ga, 256, 0, stream>>>(sbuf, tbuf, offsets, ssrc, hbuf, N);

    // ---- layer 1 ----
    gemm_mfma_wide<<<gx, 256, 0, stream>>>(hbuf, Bth1, Btl1, b1, sbuf, tbuf, N);
    agg128_kernel<1><<<ga, 256, 0, stream>>>(sbuf, tbuf, offsets, ssrc, hbuf, N);

    // ---- layer 2 ----
    gemm_mfma_narrow<<<gx, 256, 0, stream>>>(hbuf, Bth2, Btl2, b2, sbuf, tbuf, N);
    agg40_kernel<0><<<ga, 256, 0, stream>>>(sbuf, tbuf, offsets, ssrc, (float*)d_out, N);
}

// Round 5
// 337.844 us; speedup vs baseline: 1.6149x; 1.1015x over previous
//
#include <hip/hip_runtime.h>

#define N_NODES 50000
#define N_EDGES 600000

typedef short bf16x8 __attribute__((ext_vector_type(8)));
typedef float f32x4  __attribute__((ext_vector_type(4)));
typedef unsigned short u16x8 __attribute__((ext_vector_type(8)));
typedef unsigned short u16x4 __attribute__((ext_vector_type(4)));

// ---------------- bf16 helpers (RNE) ----------------
__device__ inline ushort rne_bf16(float a) {
    union { float f; unsigned u; } v; v.f = a;
    return (ushort)((v.u + 0x7FFFu + ((v.u >> 16) & 1u)) >> 16);
}
__device__ inline float bf16_to_f32(ushort h) {
    return __uint_as_float((unsigned)h << 16);
}
__device__ inline void split_bf16(float a, ushort& hi, ushort& lo) {
    hi = rne_bf16(a);
    float hv = bf16_to_f32(hi);
    lo = rne_bf16(a - hv);
}

// ---------------- CSR build ----------------

__global__ void count_deg_kernel(const int* __restrict__ dst, int* __restrict__ deg, int ne) {
    int e = blockIdx.x * blockDim.x + threadIdx.x;
    if (e < ne) atomicAdd(&deg[dst[e]], 1);
}

__global__ __launch_bounds__(256) void block_sums_kernel(const int* __restrict__ deg,
                                                         int* __restrict__ bsum, int n) {
    __shared__ int s[256];
    int t = threadIdx.x;
    int i = blockIdx.x * 256 + t;
    s[t] = (i < n) ? deg[i] : 0;
    __syncthreads();
    #pragma unroll
    for (int d = 128; d > 0; d >>= 1) {
        if (t < d) s[t] += s[t + d];
        __syncthreads();
    }
    if (t == 0) bsum[blockIdx.x] = s[0];
}

__global__ __launch_bounds__(256) void scan_bsums_kernel(const int* __restrict__ bsum,
                                                         int* __restrict__ base, int nb,
                                                         int* __restrict__ off, int n) {
    __shared__ int s[256];
    int t = threadIdx.x;
    int v = (t < nb) ? bsum[t] : 0;
    s[t] = v;
    __syncthreads();
    #pragma unroll
    for (int d = 1; d < 256; d <<= 1) {
        int x = (t >= d) ? s[t - d] : 0;
        __syncthreads();
        s[t] += x;
        __syncthreads();
    }
    if (t < nb) base[t] = s[t] - v;
    if (t == 255) off[n] = s[255];
}

__global__ __launch_bounds__(256) void scatter_offsets_kernel(const int* __restrict__ deg,
                                                              const int* __restrict__ base,
                                                              int* __restrict__ off,
                                                              int* __restrict__ cur, int n) {
    __shared__ int s[256];
    int t = threadIdx.x;
    int i = blockIdx.x * 256 + t;
    int v = (i < n) ? deg[i] : 0;
    s[t] = v;
    __syncthreads();
    #pragma unroll
    for (int d = 1; d < 256; d <<= 1) {
        int x = (t >= d) ? s[t - d] : 0;
        __syncthreads();
        s[t] += x;
        __syncthreads();
    }
    if (i < n) {
        int excl = s[t] - v + base[blockIdx.x];
        off[i] = excl;
        cur[i] = excl;
    }
}

__global__ void fill_csr_kernel(const int* __restrict__ src, const int* __restrict__ dst,
                                int* __restrict__ cur, int* __restrict__ ssrc, int ne) {
    int e = blockIdx.x * blockDim.x + threadIdx.x;
    if (e < ne) {
        int p = atomicAdd(&cur[dst[e]], 1);
        ssrc[p] = src[e];
    }
}

// ---------------- weight pre-convert ----------------
__global__ void convert_w_kernel(const float* __restrict__ Ws, const float* __restrict__ Wn,
                                 int dout, ushort* __restrict__ Bth, ushort* __restrict__ Btl) {
    int n = blockIdx.x;
    int k = threadIdx.x;
    float w = (n < dout) ? Ws[(long)k * dout + n] : Wn[(long)k * dout + (n - dout)];
    ushort hi, lo;
    split_bf16(w, hi, lo);
    Bth[n * 128 + k] = hi;
    Btl[n * 128 + k] = lo;
}

// ---------------- split-bf16 MFMA dual GEMM ----------------
// S = A@Ws + bias (fp32), T = A@Wn (stored bf16 for the cheap gather).

#define KDIM 128
#define BKC  32
#define APAD 40

__device__ inline void stage_a_tile(const float* __restrict__ A, int bm, int M, int k0,
                                    ushort* __restrict__ Ahi, ushort* __restrict__ Alo, int tid) {
    int m  = tid >> 2;
    int kq = (tid & 3) * 8;
    int grow = bm + m;
    float f[8];
    if (grow < M) {
        const float* ap = A + (long)grow * KDIM + k0 + kq;
        float4 a0 = *(const float4*)ap;
        float4 a1 = *(const float4*)(ap + 4);
        f[0] = a0.x; f[1] = a0.y; f[2] = a0.z; f[3] = a0.w;
        f[4] = a1.x; f[5] = a1.y; f[6] = a1.z; f[7] = a1.w;
    } else {
        #pragma unroll
        for (int i = 0; i < 8; ++i) f[i] = 0.f;
    }
    ushort h[8], l[8];
    #pragma unroll
    for (int i = 0; i < 8; ++i) split_bf16(f[i], h[i], l[i]);
    uint4 hw, lw;
    hw.x = (unsigned)h[0] | ((unsigned)h[1] << 16);
    hw.y = (unsigned)h[2] | ((unsigned)h[3] << 16);
    hw.z = (unsigned)h[4] | ((unsigned)h[5] << 16);
    hw.w = (unsigned)h[6] | ((unsigned)h[7] << 16);
    lw.x = (unsigned)l[0] | ((unsigned)l[1] << 16);
    lw.y = (unsigned)l[2] | ((unsigned)l[3] << 16);
    lw.z = (unsigned)l[4] | ((unsigned)l[5] << 16);
    lw.w = (unsigned)l[6] | ((unsigned)l[7] << 16);
    *(uint4*)&Ahi[m * APAD + kq] = hw;
    *(uint4*)&Alo[m * APAD + kq] = lw;
}

__global__ __launch_bounds__(256) void gemm_mfma_wide(
    const float* __restrict__ A,
    const ushort* __restrict__ Bth, const ushort* __restrict__ Btl,
    const float* __restrict__ bias,
    float* __restrict__ S, ushort* __restrict__ T, int M)
{
    __shared__ ushort Ahi[64 * APAD];
    __shared__ ushort Alo[64 * APAD];

    const int tid = threadIdx.x;
    const int bm = blockIdx.x * 64;
    const int wave = tid >> 6;
    const int lane = tid & 63;
    const int lane16 = lane & 15;
    const int quad = lane >> 4;
    const int colbase = wave * 64;

    f32x4 acc[4][4] = {};

    for (int c = 0; c < 4; ++c) {
        int k0 = c * BKC;
        __syncthreads();
        stage_a_tile(A, bm, M, k0, Ahi, Alo, tid);
        __syncthreads();

        bf16x8 ah[4], al[4];
        #pragma unroll
        for (int r = 0; r < 4; ++r) {
            int off = (16 * r + lane16) * APAD + quad * 8;
            ah[r] = *(const bf16x8*)&Ahi[off];
            al[r] = *(const bf16x8*)&Alo[off];
        }
        #pragma unroll
        for (int ct = 0; ct < 4; ++ct) {
            int col = colbase + 16 * ct + lane16;
            long boff = (long)col * KDIM + k0 + quad * 8;
            bf16x8 bh = *(const bf16x8*)(Bth + boff);
            bf16x8 bl = *(const bf16x8*)(Btl + boff);
            #pragma unroll
            for (int r = 0; r < 4; ++r) {
                acc[r][ct] = __builtin_amdgcn_mfma_f32_16x16x32_bf16(ah[r], bh, acc[r][ct], 0, 0, 0);
                acc[r][ct] = __builtin_amdgcn_mfma_f32_16x16x32_bf16(ah[r], bl, acc[r][ct], 0, 0, 0);
                acc[r][ct] = __builtin_amdgcn_mfma_f32_16x16x32_bf16(al[r], bh, acc[r][ct], 0, 0, 0);
            }
        }
    }

    #pragma unroll
    for (int ct = 0; ct < 4; ++ct) {
        int col = colbase + 16 * ct + lane16;
        bool toS = col < 128;
        float bv = toS ? bias[col] : 0.f;
        int tcol = toS ? col : col - 128;
        #pragma unroll
        for (int r = 0; r < 4; ++r) {
            #pragma unroll
            for (int i = 0; i < 4; ++i) {
                int row = bm + 16 * r + quad * 4 + i;
                if (row < M) {
                    if (toS) S[(long)row * 128 + tcol] = acc[r][ct][i] + bv;
                    else     T[(long)row * 128 + tcol] = rne_bf16(acc[r][ct][i]);
                }
            }
        }
    }
}

__global__ __launch_bounds__(256) void gemm_mfma_narrow(
    const float* __restrict__ A,
    const ushort* __restrict__ Bth, const ushort* __restrict__ Btl,
    const float* __restrict__ bias,
    float* __restrict__ S, ushort* __restrict__ T, int M)
{
    __shared__ ushort Ahi[64 * APAD];
    __shared__ ushort Alo[64 * APAD];

    const int tid = threadIdx.x;
    const int bm = blockIdx.x * 64;
    const int wave = tid >> 6;
    const int lane = tid & 63;
    const int lane16 = lane & 15;
    const int quad = lane >> 4;

    f32x4 acc[5] = {};

    for (int c = 0; c < 4; ++c) {
        int k0 = c * BKC;
        __syncthreads();
        stage_a_tile(A, bm, M, k0, Ahi, Alo, tid);
        __syncthreads();

        int aoff = (16 * wave + lane16) * APAD + quad * 8;
        bf16x8 ah = *(const bf16x8*)&Ahi[aoff];
        bf16x8 al = *(const bf16x8*)&Alo[aoff];
        #pragma unroll
        for (int ct = 0; ct < 5; ++ct) {
            int col = 16 * ct + lane16;
            long boff = (long)col * KDIM + k0 + quad * 8;
            bf16x8 bh = *(const bf16x8*)(Bth + boff);
            bf16x8 bl = *(const bf16x8*)(Btl + boff);
            acc[ct] = __builtin_amdgcn_mfma_f32_16x16x32_bf16(ah, bh, acc[ct], 0, 0, 0);
            acc[ct] = __builtin_amdgcn_mfma_f32_16x16x32_bf16(ah, bl, acc[ct], 0, 0, 0);
            acc[ct] = __builtin_amdgcn_mfma_f32_16x16x32_bf16(al, bh, acc[ct], 0, 0, 0);
        }
    }

    #pragma unroll
    for (int ct = 0; ct < 5; ++ct) {
        int col = 16 * ct + lane16;
        bool toS = col < 40;
        float bv = toS ? bias[col] : 0.f;
        int tcol = toS ? col : col - 40;
        #pragma unroll
        for (int i = 0; i < 4; ++i) {
            int row = bm + 16 * wave + quad * 4 + i;
            if (row < M) {
                if (toS) S[(long)row * 40 + tcol] = acc[ct][i] + bv;
                else     T[(long)row * 40 + tcol] = rne_bf16(acc[ct][i]);
            }
        }
    }
}

// ---------------- aggregation, wave-per-node, bf16 gather ----------------
// dout=128 (bf16 row = 256B): slot = lane>>4 (4 edges/instr, 16 lanes x 16B = 1 row),
// x2 unroll -> 8 edges in flight. Accumulate fp32.

template <int RELU>
__global__ __launch_bounds__(256) void agg128_kernel(
    const float* __restrict__ S, const ushort* __restrict__ T,
    const int* __restrict__ off, const int* __restrict__ ssrc,
    float* __restrict__ out, int nnodes)
{
    const int node = (blockIdx.x * 256 + threadIdx.x) >> 6;
    if (node >= nnodes) return;
    const int lane = threadIdx.x & 63;
    const int slot = lane >> 4;          // 0..3
    const int col8 = (lane & 15) * 8;    // 8 features per lane

    const int a = off[node];
    const int b = off[node + 1];

    f32x4 acc0a = {0,0,0,0}, acc0b = {0,0,0,0};
    f32x4 acc1a = {0,0,0,0}, acc1b = {0,0,0,0};

    int i = a;
    for (; i + 8 <= b; i += 8) {
        int s0 = ssrc[i + slot];
        int s1 = ssrc[i + 4 + slot];
        u16x8 v0 = *(const u16x8*)(T + (long)s0 * 128 + col8);
        u16x8 v1 = *(const u16x8*)(T + (long)s1 * 128 + col8);
        #pragma unroll
        for (int j = 0; j < 4; ++j) {
            acc0a[j] += bf16_to_f32(v0[j]);
            acc0b[j] += bf16_to_f32(v0[4 + j]);
            acc1a[j] += bf16_to_f32(v1[j]);
            acc1b[j] += bf16_to_f32(v1[4 + j]);
        }
    }
    for (; i < b; i += 4) {
        int e = i + slot;
        if (e < b) {
            int s = ssrc[e];
            u16x8 v = *(const u16x8*)(T + (long)s * 128 + col8);
            #pragma unroll
            for (int j = 0; j < 4; ++j) {
                acc0a[j] += bf16_to_f32(v[j]);
                acc0b[j] += bf16_to_f32(v[4 + j]);
            }
        }
    }
    f32x4 accA = acc0a + acc1a;
    f32x4 accB = acc0b + acc1b;

    // reduce across the 4 slots
    #pragma unroll
    for (int m = 16; m <= 32; m <<= 1) {
        #pragma unroll
        for (int j = 0; j < 4; ++j) {
            accA[j] += __shfl_xor((float)accA[j], m);
            accB[j] += __shfl_xor((float)accB[j], m);
        }
    }

    if (slot == 0) {
        int deg = b - a;
        float scale = (deg > 0) ? (1.0f / (float)deg) : 0.f;
        f32x4 sA = *(const f32x4*)(S + (long)node * 128 + col8);
        f32x4 sB = *(const f32x4*)(S + (long)node * 128 + col8 + 4);
        f32x4 rA = sA + accA * scale;
        f32x4 rB = sB + accB * scale;
        if (RELU) {
            #pragma unroll
            for (int j = 0; j < 4; ++j) {
                rA[j] = fmaxf(rA[j], 0.f);
                rB[j] = fmaxf(rB[j], 0.f);
            }
        }
        *(f32x4*)(out + (long)node * 128 + col8) = rA;
        *(f32x4*)(out + (long)node * 128 + col8 + 4) = rB;
    }
}

// dout=40 (bf16 row = 80B): 10 lanes/row (4 bf16 each), slot = lane/10 (6 edges/instr).
template <int RELU>
__global__ __launch_bounds__(256) void agg40_kernel(
    const float* __restrict__ S, const ushort* __restrict__ T,
    const int* __restrict__ off, const int* __restrict__ ssrc,
    float* __restrict__ out, int nnodes)
{
    const int node = (blockIdx.x * 256 + threadIdx.x) >> 6;
    if (node >= nnodes) return;
    const int lane = threadIdx.x & 63;
    const bool active = lane < 60;
    const int slot = active ? (lane / 10) : 5;   // 0..5
    const int fi = lane % 10;
    const int fo = fi * 4;

    const int a = off[node];
    const int b = off[node + 1];

    f32x4 acc0 = {0,0,0,0}, acc1 = {0,0,0,0};

    int i = a;
    for (; i + 12 <= b; i += 12) {
        int s0 = ssrc[i + slot];
        int s1 = ssrc[i + 6 + slot];
        u16x4 v0 = *(const u16x4*)(T + (long)s0 * 40 + fo);
        u16x4 v1 = *(const u16x4*)(T + (long)s1 * 40 + fo);
        if (active) {
            #pragma unroll
            for (int j = 0; j < 4; ++j) {
                acc0[j] += bf16_to_f32(v0[j]);
                acc1[j] += bf16_to_f32(v1[j]);
            }
        }
    }
    for (; i < b; i += 6) {
        int e = i + slot;
        if (active && e < b) {
            int s = ssrc[e];
            u16x4 v = *(const u16x4*)(T + (long)s * 40 + fo);
            #pragma unroll
            for (int j = 0; j < 4; ++j) acc0[j] += bf16_to_f32(v[j]);
        }
    }
    f32x4 acc = acc0 + acc1;

    f32x4 tot = acc;
    #pragma unroll
    for (int d = 10; d <= 50; d += 10) {
        int srcl = fi + d;
        #pragma unroll
        for (int j = 0; j < 4; ++j) tot[j] += __shfl((float)acc[j], srcl);
    }

    if (lane < 10) {
        int deg = b - a;
        float scale = (deg > 0) ? (1.0f / (float)deg) : 0.f;
        f32x4 s4 = *(const f32x4*)(S + (long)node * 40 + fo);
        f32x4 r = s4 + tot * scale;
        if (RELU) {
            #pragma unroll
            for (int j = 0; j < 4; ++j) r[j] = fmaxf(r[j], 0.f);
        }
        *(f32x4*)(out + (long)node * 40 + fo) = r;
    }
}

// ---------------- launch ----------------

extern "C" void kernel_launch(void* const* d_in, const int* in_sizes, int n_in,
                              void* d_out, int out_size, void* d_ws, size_t ws_size,
                              hipStream_t stream) {
    const float* feat = (const float*)d_in[0];
    const int*   src  = (const int*)d_in[1];
    const int*   dst  = (const int*)d_in[2];
    const float* ws0  = (const float*)d_in[3];
    const float* wn0  = (const float*)d_in[4];
    const float* b0   = (const float*)d_in[5];
    const float* ws1  = (const float*)d_in[6];
    const float* wn1  = (const float*)d_in[7];
    const float* b1   = (const float*)d_in[8];
    const float* ws2  = (const float*)d_in[9];
    const float* wn2  = (const float*)d_in[10];
    const float* b2   = (const float*)d_in[11];

    const int N = N_NODES;
    const int NE = N_EDGES;
    const int NB = (N + 255) / 256;  // 196

    char* ws = (char*)d_ws;
    int*    offsets = (int*)(ws + 0);
    int*    cursor  = (int*)(ws + 200704);
    int*    degi    = (int*)(ws + 401408);
    int*    bsum    = (int*)(ws + 601600);
    int*    bbase   = (int*)(ws + 602432);
    int*    ssrc    = (int*)(ws + 603648);
    ushort* Bth0 = (ushort*)(ws + 200704);   // overlap cursor/degi, written after CSR build
    ushort* Btl0 = (ushort*)(ws + 266240);
    ushort* Bth1 = (ushort*)(ws + 331776);
    ushort* Btl1 = (ushort*)(ws + 397312);
    ushort* Bth2 = (ushort*)(ws + 462848);
    ushort* Btl2 = (ushort*)(ws + 483328);
    float*  hbuf = (float*)(ws + 3003904);   // 25.6 MB fp32
    float*  sbuf = (float*)(ws + 28603904);  // 25.6 MB fp32
    ushort* tbuf = (ushort*)(ws + 54203904); // 12.8 MB bf16

    // ---- CSR build ----
    hipMemsetAsync(degi, 0, (size_t)N * sizeof(int), stream);
    count_deg_kernel<<<(NE + 255) / 256, 256, 0, stream>>>(dst, degi, NE);
    block_sums_kernel<<<NB, 256, 0, stream>>>(degi, bsum, N);
    scan_bsums_kernel<<<1, 256, 0, stream>>>(bsum, bbase, NB, offsets, N);
    scatter_offsets_kernel<<<NB, 256, 0, stream>>>(degi, bbase, offsets, cursor, N);
    fill_csr_kernel<<<(NE + 255) / 256, 256, 0, stream>>>(src, dst, cursor, ssrc, NE);

    // ---- weight pre-convert ----
    convert_w_kernel<<<256, 128, 0, stream>>>(ws0, wn0, 128, Bth0, Btl0);
    convert_w_kernel<<<256, 128, 0, stream>>>(ws1, wn1, 128, Bth1, Btl1);
    convert_w_kernel<<<80, 128, 0, stream>>>(ws2, wn2, 40, Bth2, Btl2);

    const int gx = (N + 63) / 64;        // 782 GEMM blocks
    const int ga = (N + 3) / 4;          // 12500 agg blocks (4 waves/block)

    // ---- layer 0 ----
    gemm_mfma_wide<<<gx, 256, 0, stream>>>(feat, Bth0, Btl0, b0, sbuf, tbuf, N);
    agg128_kernel<1><<<ga, 256, 0, stream>>>(sbuf, tbuf, offsets, ssrc, hbuf, N);

    // ---- layer 1 ----
    gemm_mfma_wide<<<gx, 256, 0, stream>>>(hbuf, Bth1, Btl1, b1, sbuf, tbuf, N);
    agg128_kernel<1><<<ga, 256, 0, stream>>>(sbuf, tbuf, offsets, ssrc, hbuf, N);

    // ---- layer 2 ----
    gemm_mfma_narrow<<<gx, 256, 0, stream>>>(hbuf, Bth2, Btl2, b2, sbuf, tbuf, N);
    agg40_kernel<0><<<ga, 256, 0, stream>>>(sbuf, tbuf, offsets, ssrc, (float*)d_out, N);
}